// Round 6
// baseline (928.722 us; speedup 1.0000x reference)
//
#include <hip/hip_runtime.h>
#include <stdint.h>

#define RELS 8
#define F 256
#define KDIM 2304        // 8*256 stacked relations + 256 root/self columns
#define NKT 36           // KDIM / 64 k-tiles
#define TSZ 8192         // shorts per Wt (tile,kt) chunk: 128 rows x 64 cols
#define SCAN_CHUNK 1024  // bins per scan1 block (256 threads x 4)

// Wt global layout: tiled + FRAGMENT-MAJOR (round-4 verified). chunk(tile,kt)
// is contiguous 16KB holding rows [0,128) x k-units [0,8) (unit = 8 shorts):
//   frag = (row>>6)*8 + ((row>>4)&3)*2 + (unit>>2)      // in [0,16)
//   lane = (unit&3)*16 + (row&15)                       // in [0,64)
//   addr = chunk_base + frag*512 + lane*8 + (k&7)       // shorts
// A wave reads fragment (mi,kk) as ONE contiguous 1KB dwordx4 straight into
// the mfma_16x16x32 operand layout. k_fused uses the same layout for its
// 64-row LDS A-slice (chunk = 8 frags = 4096 shorts), with a dl-group XOR
// swizzle (write and read both XOR (dlgrp<<4) shorts) to spread the gather
// stores across 16 banks instead of 2.

typedef __attribute__((ext_vector_type(8))) short short8;
typedef __attribute__((ext_vector_type(4))) float f32x4;
typedef __attribute__((ext_vector_type(2))) unsigned int uint2v;

__device__ __forceinline__ unsigned short f2bf(float f) {
  union { float f; unsigned int u; } v; v.f = f;
  unsigned int u = v.u;
  if ((u & 0x7f800000u) == 0x7f800000u) return (unsigned short)(u >> 16);
  return (unsigned short)((u + 0x7fffu + ((u >> 16) & 1u)) >> 16);  // RNE
}
__device__ __forceinline__ float bf2f(unsigned short b) {
  union { unsigned int u; float f; } v; v.u = ((unsigned int)b) << 16; return v.f;
}

// ---- x fp32 -> compact bf16 [N,256] (small L3-resident gather source)
__global__ void k_xb(const float* __restrict__ x, unsigned short* __restrict__ xb, int N) {
  int tid = blockIdx.x * blockDim.x + threadIdx.x;
  int n = tid >> 6, q = tid & 63;
  if (n >= N) return;
  const float4 v = *(const float4*)&x[(size_t)n * F + q * 4];
  ushort4 o;
  o.x = f2bf(v.x); o.y = f2bf(v.y); o.z = f2bf(v.z); o.w = f2bf(v.w);
  *(ushort4*)&xb[(size_t)n * F + q * 4] = o;
}

// ---- weight convert+transpose into tiled+fragment-major layout ----
// Wt content: row n (output col), k<2048: W[k][n]; else root[k-2048][n].
__global__ void k_wt(const float* __restrict__ W, const float* __restrict__ root,
                     unsigned short* __restrict__ Wt, int Ncols) {
  int tid = blockIdx.x * blockDim.x + threadIdx.x;
  int total = Ncols * KDIM;
  if (tid >= total) return;
  int n = tid / KDIM, k = tid - n * KDIM;
  float v = (k < 2048) ? W[(size_t)k * Ncols + n] : root[(size_t)(k - 2048) * Ncols + n];
  int tile = n >> 7, row = n & 127;
  int kt = k >> 6, c = k & 63;
  int u = c >> 3, w = c & 7;
  int frag = ((row >> 6) << 3) + (((row >> 4) & 3) << 1) + (u >> 2);
  int dl = ((u & 3) << 4) + (row & 15);
  Wt[(size_t)(tile * NKT + kt) * TSZ + frag * 512 + dl * 8 + w] = f2bf(v);
}

// ---- CSR build ----
__global__ void k_count(const int* __restrict__ ei, const int* __restrict__ et,
                        int* __restrict__ cnt, int E) {
  int e = blockIdx.x * blockDim.x + threadIdx.x;
  if (e >= E) return;
  int bin = ei[E + e] * RELS + et[e];
  atomicAdd(&cnt[bin], 1);
}

__global__ void k_scan1(const int* __restrict__ cnt, int* __restrict__ start,
                        int* __restrict__ bsum, int nb) {
  __shared__ int tsum[256];
  const int t = threadIdx.x;
  const int idx = blockIdx.x * SCAN_CHUNK + t * 4;
  int v[4]; int s = 0;
#pragma unroll
  for (int i = 0; i < 4; i++) { v[i] = (idx + i < nb) ? cnt[idx + i] : 0; s += v[i]; }
  tsum[t] = s;
  __syncthreads();
  for (int d = 1; d < 256; d <<= 1) {
    int a = (t >= d) ? tsum[t - d] : 0;
    __syncthreads();
    tsum[t] += a;
    __syncthreads();
  }
  int ex = (t > 0) ? tsum[t - 1] : 0;
#pragma unroll
  for (int i = 0; i < 4; i++) { if (idx + i < nb) start[idx + i] = ex; ex += v[i]; }
  if (t == 255) bsum[blockIdx.x] = tsum[255];
}

__global__ void k_scan2(int* __restrict__ bsum, int nblocks) {
  __shared__ int sh[1024];
  const int t = threadIdx.x;
  sh[t] = (t < nblocks) ? bsum[t] : 0;
  __syncthreads();
  for (int d = 1; d < 1024; d <<= 1) {
    int a = (t >= d) ? sh[t - d] : 0;
    __syncthreads();
    sh[t] += a;
    __syncthreads();
  }
  if (t < nblocks) bsum[t] = (t > 0) ? sh[t - 1] : 0;
  if (t == 1023) bsum[nblocks] = sh[1023];
}

__global__ void k_scan3(int* __restrict__ start, const int* __restrict__ bsum,
                        int nb, int nblocks) {
  int i = blockIdx.x * blockDim.x + threadIdx.x;
  if (i < nb) start[i] += bsum[i >> 10];
  if (i == 0) start[nb] = bsum[nblocks];
}

__global__ void k_scatter(const int* __restrict__ ei, const int* __restrict__ et,
                          const int* __restrict__ start, int* __restrict__ cur,
                          int* __restrict__ ssrc, int E) {
  int e = blockIdx.x * blockDim.x + threadIdx.x;
  if (e >= E) return;
  int bin = ei[E + e] * RELS + et[e];
  int p = atomicAdd(&cur[bin], 1);
  ssrc[start[bin] + p] = ei[e];
}

// ---- FUSED per-tile kernel: aggregate -> LDS slice -> MFMA, per relation ----
// Round-5 post-mortem: gather was a serial 16-bin dependent-load chain per
// wave (~92us unhidden latency) with 1.5 blocks/CU. Fixes here:
//  (1) 4-way interleaved bin chains per wave (lockstep loop, static regs):
//      4 ssrc + 4 feature loads in flight -> ~4x less exposed latency.
//  (2) 64-row tiles, 256 thr, 32KB slice -> 782 blocks, 3 blocks/CU,
//      48 concurrent chains/CU.
//  (3) dl-group XOR swizzle on the slice (write+read) -> gather stores hit
//      16 banks instead of 2 (round 5: 1.26e7 conflict cycles).
// Accumulator lives across all 9 relation slices; k-order identical.
template<int NI, bool RELU, bool OUTBF16>
__global__ __launch_bounds__(256, 3) void k_fused(
    const unsigned short* __restrict__ src, const unsigned short* __restrict__ Wt,
    const int* __restrict__ start, const int* __restrict__ ssrc,
    const float* __restrict__ bias, void* __restrict__ outp, int Nreal) {
  __shared__ unsigned short slice[4 * 4096];   // 32 KB: [chunk][frag<8][512]
  const int t = threadIdx.x;
  const int lane = t & 63, wid = t >> 6;       // 4 waves
  const int m0 = blockIdx.x * 64;
  const int c15 = lane & 15, quad = lane >> 4;
  const int wn = wid * (NI * 16);              // wave's output column base
  // gather constants: lane covers feature cols [4*lane, 4*lane+4)
  const int gc = lane >> 4;                    // k-chunk within slice
  const int gL = lane & 15;
  const int gFragLo = gL >> 3;                 // unit bit of frag
  const int gDlHi = ((gL >> 1) & 3) << 4;      // dl bits 4-5
  const int gW = (gL & 1) * 4;                 // short offset within unit
  const int gSwz = ((gL >> 1) & 3) << 4;       // XOR key (shorts) = dlgrp<<4

  f32x4 acc[4][NI];
#pragma unroll
  for (int i = 0; i < 4; i++)
#pragma unroll
    for (int j = 0; j < NI; j++) acc[i][j] = (f32x4)0.f;

  const unsigned short* Bt = Wt + (size_t)(wn >> 7) * NKT * TSZ + lane * 8;
  const int roff = (lane << 3) ^ ((lane >> 4 & 3) << 4);  // swizzled frag read

  for (int r = 0; r < 9; r++) {
    // ---- phase 1: build fragment-major A-slice for relation r in LDS ----
    if (r < 8) {
#pragma unroll 1
      for (int g = 0; g < 4; g++) {            // 4 groups of 4 lockstep rows
        int e0[4], e1[4]; float sc[4]; f32x4 ac[4];
#pragma unroll
        for (int c = 0; c < 4; c++) {
          int n = m0 + (wid << 4) + (g << 2) + c;
          ac[c] = (f32x4)0.f;
          if (n < Nreal) {
            int bin = n * RELS + r;
            e0[c] = start[bin]; e1[c] = start[bin + 1];
            int deg = e1[c] - e0[c];
            sc[c] = 1.0f / (float)(deg > 1 ? deg : 1);
          } else { e0[c] = 0; e1[c] = 0; sc[c] = 1.0f; }
        }
        // lockstep: one edge per active chain per iteration; 4 independent
        // ssrc loads then 4 independent feature loads in flight together.
        while ((e0[0] < e1[0]) | (e0[1] < e1[1]) |
               (e0[2] < e1[2]) | (e0[3] < e1[3])) {
          ushort4 v[4]; bool a[4];
#pragma unroll
          for (int c = 0; c < 4; c++) {
            a[c] = e0[c] < e1[c];
            if (a[c]) {
              int sA = ssrc[e0[c]];
              v[c] = *(const ushort4*)&src[(size_t)sA * F + lane * 4];
            }
          }
#pragma unroll
          for (int c = 0; c < 4; c++) {
            if (a[c]) {
              ac[c].x += bf2f(v[c].x); ac[c].y += bf2f(v[c].y);
              ac[c].z += bf2f(v[c].z); ac[c].w += bf2f(v[c].w);
              e0[c]++;
            }
          }
        }
#pragma unroll
        for (int c = 0; c < 4; c++) {
          int row = (wid << 4) + (g << 2) + c;
          int frag = (((row >> 4) & 3) << 1) | gFragLo;
          int dl = gDlHi | (row & 15);
          uint2v o;
          o.x = (unsigned)f2bf(ac[c].x * sc[c]) | ((unsigned)f2bf(ac[c].y * sc[c]) << 16);
          o.y = (unsigned)f2bf(ac[c].z * sc[c]) | ((unsigned)f2bf(ac[c].w * sc[c]) << 16);
          *(uint2v*)&slice[gc * 4096 + frag * 512 + (((dl << 3) | gW) ^ gSwz)] = o;
        }
      }
    } else {
      // self slice: raw copy of this tile's own features (4 loads in flight)
#pragma unroll 4
      for (int bi = 0; bi < 16; bi++) {
        int row = (wid << 4) + bi;
        const uint2v vv = *(const uint2v*)&src[(size_t)(m0 + row) * F + lane * 4];
        int frag = (((row >> 4) & 3) << 1) | gFragLo;
        int dl = gDlHi | (row & 15);
        *(uint2v*)&slice[gc * 4096 + frag * 512 + (((dl << 3) | gW) ^ gSwz)] = vv;
      }
    }
    __syncthreads();
    // ---- phase 2: MFMA slice x Wt chunks kt = r*4 .. r*4+3 ----
#pragma unroll
    for (int c = 0; c < 4; c++) {
      const unsigned short* bc = Bt + (size_t)(r * 4 + c) * TSZ;
#pragma unroll
      for (int kk = 0; kk < 2; kk++) {
        short8 bfr[NI], afr[4];
#pragma unroll
        for (int ni = 0; ni < NI; ni++) {
          int rB = (wn & 127) + ni * 16;
          int fB = ((rB >> 6) << 3) + (((rB >> 4) & 3) << 1) + kk;
          bfr[ni] = *(const short8*)(bc + fB * 512);
        }
#pragma unroll
        for (int mi = 0; mi < 4; mi++) {
          int fA = (mi << 1) + kk;
          afr[mi] = *(const short8*)&slice[c * 4096 + fA * 512 + roff];
        }
#pragma unroll
        for (int mi = 0; mi < 4; mi++)
#pragma unroll
          for (int ni = 0; ni < NI; ni++)
            acc[mi][ni] = __builtin_amdgcn_mfma_f32_16x16x32_bf16(
                afr[mi], bfr[ni], acc[mi][ni], 0, 0, 0);
      }
    }
    __syncthreads();   // before overwriting the slice with the next relation
  }

  // ---- epilogue: bias (+relu) and store; output width = NI*64 ----
  const int Nld = NI * 64;
#pragma unroll
  for (int mi = 0; mi < 4; mi++) {
#pragma unroll
    for (int ni = 0; ni < NI; ni++) {
      int n = wn + ni * 16 + c15;
      float bv = bias[n];
#pragma unroll
      for (int rr = 0; rr < 4; rr++) {
        int m = m0 + mi * 16 + quad * 4 + rr;
        if (m < Nreal) {
          float v = acc[mi][ni][rr] + bv;
          if (RELU) v = v > 0.f ? v : 0.f;
          if (OUTBF16) ((unsigned short*)outp)[(size_t)m * Nld + n] = f2bf(v);
          else         ((float*)outp)[(size_t)m * Nld + n] = v;
        }
      }
    }
  }
}

extern "C" void kernel_launch(void* const* d_in, const int* in_sizes, int n_in,
                              void* d_out, int out_size, void* d_ws, size_t ws_size,
                              hipStream_t stream) {
  const float* x     = (const float*)d_in[0];
  const int*   ei    = (const int*)d_in[1];   // [2, E]: src row then dst row
  const int*   et    = (const int*)d_in[2];   // [E]
  const float* W1    = (const float*)d_in[3]; // [2048,256]
  const float* root1 = (const float*)d_in[4]; // [256,256]
  const float* b1    = (const float*)d_in[5];
  const float* W2    = (const float*)d_in[6]; // [2048,128]
  const float* root2 = (const float*)d_in[7]; // [256,128]
  const float* b2    = (const float*)d_in[8];

  const int N = in_sizes[0] / F;              // 50000
  const int E = in_sizes[2];                  // 800000
  const int nbins = N * RELS;                 // 400000
  const int Mpad = ((N + 127) / 128) * 128;   // 50048 (also /64 exact)
  const int nsb = (nbins + SCAN_CHUNK - 1) / SCAN_CHUNK;

  char* base = (char*)d_ws;
  size_t off = 0;
  auto alloc = [&](size_t bytes) {
    void* r = base + off;
    off = (off + bytes + 511) & ~(size_t)511;
    return r;
  };
  unsigned short* Wt1  = (unsigned short*)alloc((size_t)2 * NKT * TSZ * 2);  // 256 cols
  unsigned short* Wt2  = (unsigned short*)alloc((size_t)1 * NKT * TSZ * 2);  // 128 cols
  int*            cnt  = (int*)alloc((size_t)nbins * 4);
  int*            strt = (int*)alloc((size_t)(nbins + 1) * 4);
  int*            bsum = (int*)alloc((size_t)(nsb + 1) * 4);
  int*            ssrc = (int*)alloc((size_t)E * 4);
  unsigned short* xb   = (unsigned short*)alloc((size_t)Mpad * F * 2);  // bf16 x
  unsigned short* h    = (unsigned short*)alloc((size_t)Mpad * F * 2);  // bf16 h
  (void)ws_size; (void)n_in; (void)out_size;

  hipMemsetAsync(cnt, 0, (size_t)nbins * 4, stream);
  k_xb<<<(N * 64 + 255) / 256, 256, 0, stream>>>(x, xb, N);
  k_wt<<<(256 * KDIM + 255) / 256, 256, 0, stream>>>(W1, root1, Wt1, 256);
  k_wt<<<(128 * KDIM + 255) / 256, 256, 0, stream>>>(W2, root2, Wt2, 128);
  k_count<<<(E + 255) / 256, 256, 0, stream>>>(ei, et, cnt, E);
  k_scan1<<<nsb, 256, 0, stream>>>(cnt, strt, bsum, nbins);
  k_scan2<<<1, 1024, 0, stream>>>(bsum, nsb);
  k_scan3<<<(nbins + 255) / 256, 256, 0, stream>>>(strt, bsum, nbins, nsb);
  hipMemsetAsync(cnt, 0, (size_t)nbins * 4, stream);  // reuse as cursor
  k_scatter<<<(E + 255) / 256, 256, 0, stream>>>(ei, et, strt, cnt, ssrc, E);

  // Layer 1: gather x (bf16, L3-resident) -> h. No A materialization.
  k_fused<4, true, true><<<Mpad / 64, 256, 0, stream>>>(xb, Wt1, strt, ssrc, b1, h, N);
  // Layer 2: gather h -> output (fp32).
  k_fused<2, false, false><<<Mpad / 64, 256, 0, stream>>>(h, Wt2, strt, ssrc, b2, d_out, N);
}

// Round 7
// 622.263 us; speedup vs baseline: 1.4925x; 1.4925x over previous
//
#include <hip/hip_runtime.h>
#include <stdint.h>

#define RELS 8
#define F 256
#define KDIM 2304        // 8*256 stacked relations + 256 root/self columns
#define NKT 36           // KDIM / 64 k-tiles
#define TSZ 8192         // shorts per Wt (tile,kt) chunk: 128 rows x 64 cols
#define SCAN_CHUNK 1024  // bins per scan1 block (256 threads x 4)

// CSR bin order is RELATION-MAJOR: bin = rel*N + dst. For a fixed relation,
// the edges of any contiguous dst-row range are CONTIGUOUS in ssrc2 -> the
// fused kernel's gather is a sequential stream, software-pipelined 8-deep,
// instead of per-bin dependent pointer chases (round 5/6 failure mode).
// ssrc2 entry: src_id (bits 0..19) | (dst & 63) << 20.
//
// Wt global layout: tiled + FRAGMENT-MAJOR (round-4 verified). chunk(tile,kt)
// is contiguous 16KB holding rows [0,128) x k-units [0,8) (unit = 8 shorts):
//   frag = (row>>6)*8 + ((row>>4)&3)*2 + (unit>>2)
//   lane = (unit&3)*16 + (row&15)
//   addr = chunk_base + frag*512 + lane*8 + (k&7)       // shorts
// k_fused's 64-row LDS A-slice uses the same mapping (row>>6 = 0) with the
// round-6-verified dl-group XOR swizzle on write and read.

typedef __attribute__((ext_vector_type(8))) short short8;
typedef __attribute__((ext_vector_type(4))) float f32x4;
typedef __attribute__((ext_vector_type(2))) unsigned int uint2v;

__device__ __forceinline__ unsigned short f2bf(float f) {
  union { float f; unsigned int u; } v; v.f = f;
  unsigned int u = v.u;
  if ((u & 0x7f800000u) == 0x7f800000u) return (unsigned short)(u >> 16);
  return (unsigned short)((u + 0x7fffu + ((u >> 16) & 1u)) >> 16);  // RNE
}
__device__ __forceinline__ float bf2f(unsigned short b) {
  union { unsigned int u; float f; } v; v.u = ((unsigned int)b) << 16; return v.f;
}

// ---- x fp32 -> compact bf16 [N,256] (small L3-resident gather source)
__global__ void k_xb(const float* __restrict__ x, unsigned short* __restrict__ xb, int N) {
  int tid = blockIdx.x * blockDim.x + threadIdx.x;
  int n = tid >> 6, q = tid & 63;
  if (n >= N) return;
  const float4 v = *(const float4*)&x[(size_t)n * F + q * 4];
  ushort4 o;
  o.x = f2bf(v.x); o.y = f2bf(v.y); o.z = f2bf(v.z); o.w = f2bf(v.w);
  *(ushort4*)&xb[(size_t)n * F + q * 4] = o;
}

// ---- weight convert+transpose into tiled+fragment-major layout ----
// Wt content: row n (output col), k<2048: W[k][n]; else root[k-2048][n].
__global__ void k_wt(const float* __restrict__ W, const float* __restrict__ root,
                     unsigned short* __restrict__ Wt, int Ncols) {
  int tid = blockIdx.x * blockDim.x + threadIdx.x;
  int total = Ncols * KDIM;
  if (tid >= total) return;
  int n = tid / KDIM, k = tid - n * KDIM;
  float v = (k < 2048) ? W[(size_t)k * Ncols + n] : root[(size_t)(k - 2048) * Ncols + n];
  int tile = n >> 7, row = n & 127;
  int kt = k >> 6, c = k & 63;
  int u = c >> 3, w = c & 7;
  int frag = ((row >> 6) << 3) + (((row >> 4) & 3) << 1) + (u >> 2);
  int dl = ((u & 3) << 4) + (row & 15);
  Wt[(size_t)(tile * NKT + kt) * TSZ + frag * 512 + dl * 8 + w] = f2bf(v);
}

// ---- CSR build (relation-major bins) ----
__global__ void k_count(const int* __restrict__ ei, const int* __restrict__ et,
                        int* __restrict__ cnt, int E, int N) {
  int e = blockIdx.x * blockDim.x + threadIdx.x;
  if (e >= E) return;
  int bin = et[e] * N + ei[E + e];
  atomicAdd(&cnt[bin], 1);
}

__global__ void k_scan1(const int* __restrict__ cnt, int* __restrict__ start,
                        int* __restrict__ bsum, int nb) {
  __shared__ int tsum[256];
  const int t = threadIdx.x;
  const int idx = blockIdx.x * SCAN_CHUNK + t * 4;
  int v[4]; int s = 0;
#pragma unroll
  for (int i = 0; i < 4; i++) { v[i] = (idx + i < nb) ? cnt[idx + i] : 0; s += v[i]; }
  tsum[t] = s;
  __syncthreads();
  for (int d = 1; d < 256; d <<= 1) {
    int a = (t >= d) ? tsum[t - d] : 0;
    __syncthreads();
    tsum[t] += a;
    __syncthreads();
  }
  int ex = (t > 0) ? tsum[t - 1] : 0;
#pragma unroll
  for (int i = 0; i < 4; i++) { if (idx + i < nb) start[idx + i] = ex; ex += v[i]; }
  if (t == 255) bsum[blockIdx.x] = tsum[255];
}

__global__ void k_scan2(int* __restrict__ bsum, int nblocks) {
  __shared__ int sh[1024];
  const int t = threadIdx.x;
  sh[t] = (t < nblocks) ? bsum[t] : 0;
  __syncthreads();
  for (int d = 1; d < 1024; d <<= 1) {
    int a = (t >= d) ? sh[t - d] : 0;
    __syncthreads();
    sh[t] += a;
    __syncthreads();
  }
  if (t < nblocks) bsum[t] = (t > 0) ? sh[t - 1] : 0;
  if (t == 1023) bsum[nblocks] = sh[1023];
}

__global__ void k_scan3(int* __restrict__ start, const int* __restrict__ bsum,
                        int nb, int nblocks) {
  int i = blockIdx.x * blockDim.x + threadIdx.x;
  if (i < nb) start[i] += bsum[i >> 10];
  if (i == 0) start[nb] = bsum[nblocks];
}

__global__ void k_scatter(const int* __restrict__ ei, const int* __restrict__ et,
                          const int* __restrict__ start, int* __restrict__ cur,
                          unsigned int* __restrict__ ssrc2, int E, int N) {
  int e = blockIdx.x * blockDim.x + threadIdx.x;
  if (e >= E) return;
  int dst = ei[E + e];
  int bin = et[e] * N + dst;
  int p = atomicAdd(&cur[bin], 1);
  ssrc2[start[bin] + p] = (unsigned)ei[e] | ((unsigned)(dst & 63) << 20);
}

// ---- FUSED per-tile kernel: streaming aggregate -> LDS slice -> MFMA ----
// Per relation r, each wave owns 16 of the block's 64 rows; relation-major
// bins make those rows' edges ONE contiguous ssrc2 range. The range is
// streamed with an 8-edge pipelined window (ssrc2 packed ids loaded 2 blocks
// ahead, feature rows 1 block ahead -> 8-16 feature loads in flight/wave,
// static register indexing). Rows arrive in ascending order; a uniform
// row-change flush writes the finished row (scaled, bf16-packed) into the
// fragment-major XOR-swizzled slice. Zero-fill is wave-ownership-partitioned
// (wave wid owns frags {2wid,2wid+1}: (row>>4)&3 == wid), so no pre-barrier.
// Accumulator spans all 9 relation slices; per-bin edge order == rounds 0-6.
template<int NI, bool RELU, bool OUTBF16>
__global__ __launch_bounds__(256, 3) void k_fused(
    const unsigned short* __restrict__ src, const unsigned short* __restrict__ Wt,
    const int* __restrict__ start, const unsigned int* __restrict__ ssrc2,
    const float* __restrict__ bias, void* __restrict__ outp, int Nn) {
  __shared__ unsigned short slice[4 * 4096];   // 32 KB: [chunk][frag<8][512]
  const int t = threadIdx.x;
  const int lane = t & 63, wid = t >> 6;       // 4 waves, 16 rows each
  const int m0 = blockIdx.x * 64;
  const int c15 = lane & 15, quad = lane >> 4;
  const int wn = wid * (NI * 16);              // wave's output column base
  // gather constants: lane covers feature cols [4*lane, 4*lane+4)
  const int gc = lane >> 4;                    // k-chunk within slice
  const int gL = lane & 15;
  const int gFragLo = gL >> 3;
  const int gDlHi = ((gL >> 1) & 3) << 4;
  const int gW = (gL & 1) * 4;
  const int gSwz = ((gL >> 1) & 3) << 4;       // XOR key (shorts)

  f32x4 acc[4][NI];
#pragma unroll
  for (int i = 0; i < 4; i++)
#pragma unroll
    for (int j = 0; j < NI; j++) acc[i][j] = (f32x4)0.f;

  const unsigned short* Bt = Wt + (size_t)(wn >> 7) * NKT * TSZ + lane * 8;
  const int roff = (lane << 3) ^ ((lane >> 4 & 3) << 4);  // swizzled frag read

#define LDPK(P_, eo_)                                                        \
  { _Pragma("unroll") for (int j = 0; j < 8; j++) P_[j] = ssrc2[(eo_) + j]; }
#define LDFV(Fv_, P_)                                                        \
  { _Pragma("unroll") for (int j = 0; j < 8; j++)                            \
      Fv_[j] = *(const ushort4*)&src[(size_t)(P_[j] & 0xFFFFFu) * F + lane * 4]; }
#define FLUSHROW()                                                           \
  {                                                                          \
    float s_ = 1.0f / (float)(cnt > 1 ? cnt : 1);                            \
    int frag_ = (((curDl >> 4) & 3) << 1) | gFragLo;                         \
    int dloc_ = gDlHi | (curDl & 15);                                        \
    uint2v o_;                                                               \
    o_.x = (unsigned)f2bf(accR.x * s_) | ((unsigned)f2bf(accR.y * s_) << 16);\
    o_.y = (unsigned)f2bf(accR.z * s_) | ((unsigned)f2bf(accR.w * s_) << 16);\
    *(uint2v*)&slice[gc * 4096 + frag_ * 512 + (((dloc_ << 3) | gW) ^ gSwz)] = o_; \
  }
#define PROC(pk_, fv_)                                                       \
  {                                                                          \
    int dl_ = (int)((pk_) >> 20);                                            \
    if (dl_ != curDl) {                                                      \
      if (curDl >= 0) FLUSHROW();                                            \
      curDl = dl_; cnt = 0;                                                  \
      accR.x = 0.f; accR.y = 0.f; accR.z = 0.f; accR.w = 0.f;                \
    }                                                                        \
    accR.x += bf2f((fv_).x); accR.y += bf2f((fv_).y);                        \
    accR.z += bf2f((fv_).z); accR.w += bf2f((fv_).w);                        \
    cnt++;                                                                   \
  }
#define PROC8(P_, Fv_)                                                       \
  { _Pragma("unroll") for (int j = 0; j < 8; j++) PROC(P_[j], Fv_[j]); }
#define CP8(D_, S_)                                                          \
  { _Pragma("unroll") for (int j = 0; j < 8; j++) D_[j] = S_[j]; }

  for (int r = 0; r < 9; r++) {
    // ---- phase 1: build fragment-major A-slice for relation r in LDS ----
    if (r < 8) {
      // zero-fill ONLY this wave's frags {2wid, 2wid+1} in all 4 chunks
      short8 z8 = {0, 0, 0, 0, 0, 0, 0, 0};
#pragma unroll
      for (int z = 0; z < 8; z++)
        *(short8*)&slice[(z >> 1) * 4096 + (wid * 2 + (z & 1)) * 512 + lane * 8] = z8;

      int rA = m0 + wid * 16;
      int rB = rA + 16;
      rA = rA < Nn ? rA : Nn;
      rB = rB < Nn ? rB : Nn;
      int e  = start[r * Nn + rA];
      int eE = start[r * Nn + rB];

      int curDl = -1, cnt = 0;
      f32x4 accR; accR.x = accR.y = accR.z = accR.w = 0.f;

      unsigned pkA[8], pkB[8]; ushort4 fvA[8];
      if (e + 8 <= eE) { LDPK(pkA, e); LDFV(fvA, pkA); }
      if (e + 16 <= eE) LDPK(pkB, e + 8);
      while (e + 24 <= eE) {
        ushort4 fvB[8]; LDFV(fvB, pkB);   // block k+1 features (pkB landed)
        unsigned pkC[8]; LDPK(pkC, e + 16); // block k+2 ids, lands next iter
        PROC8(pkA, fvA);                  // process block k (waits on fvA only)
        CP8(pkA, pkB); CP8(fvA, fvB); CP8(pkB, pkC);
        e += 8;
      }
      if (e + 16 <= eE) {                 // 16..23 left: blocks A,B valid
        ushort4 fvB[8]; LDFV(fvB, pkB);
        PROC8(pkA, fvA);
        CP8(pkA, pkB); CP8(fvA, fvB);
        e += 8;
      }
      if (e + 8 <= eE) {                  // 8..15 left: block A valid
        PROC8(pkA, fvA);
        e += 8;
      }
      for (; e < eE; e++) {               // tail < 8
        unsigned p_ = ssrc2[e];
        ushort4 f_ = *(const ushort4*)&src[(size_t)(p_ & 0xFFFFFu) * F + lane * 4];
        PROC(p_, f_);
      }
      if (curDl >= 0) FLUSHROW();
    } else {
      // self slice: raw copy of this tile's own features (rows owned by wave)
#pragma unroll 4
      for (int bi = 0; bi < 16; bi++) {
        int row = (wid << 4) + bi;
        const uint2v vv = *(const uint2v*)&src[(size_t)(m0 + row) * F + lane * 4];
        int frag = (((row >> 4) & 3) << 1) | gFragLo;
        int dl = gDlHi | (row & 15);
        *(uint2v*)&slice[gc * 4096 + frag * 512 + (((dl << 3) | gW) ^ gSwz)] = vv;
      }
    }
    __syncthreads();
    // ---- phase 2: MFMA slice x Wt chunks kt = r*4 .. r*4+3 ----
#pragma unroll
    for (int c = 0; c < 4; c++) {
      const unsigned short* bc = Bt + (size_t)(r * 4 + c) * TSZ;
#pragma unroll
      for (int kk = 0; kk < 2; kk++) {
        short8 bfr[NI], afr[4];
#pragma unroll
        for (int ni = 0; ni < NI; ni++) {
          int rB2 = (wn & 127) + ni * 16;
          int fB = ((rB2 >> 6) << 3) + (((rB2 >> 4) & 3) << 1) + kk;
          bfr[ni] = *(const short8*)(bc + fB * 512);
        }
#pragma unroll
        for (int mi = 0; mi < 4; mi++) {
          int fA = (mi << 1) + kk;
          afr[mi] = *(const short8*)&slice[c * 4096 + fA * 512 + roff];
        }
#pragma unroll
        for (int mi = 0; mi < 4; mi++)
#pragma unroll
          for (int ni = 0; ni < NI; ni++)
            acc[mi][ni] = __builtin_amdgcn_mfma_f32_16x16x32_bf16(
                afr[mi], bfr[ni], acc[mi][ni], 0, 0, 0);
      }
    }
    __syncthreads();   // before overwriting the slice with the next relation
  }
#undef LDPK
#undef LDFV
#undef FLUSHROW
#undef PROC
#undef PROC8
#undef CP8

  // ---- epilogue: bias (+relu) and store; output width = NI*64 ----
  const int Nld = NI * 64;
#pragma unroll
  for (int mi = 0; mi < 4; mi++) {
#pragma unroll
    for (int ni = 0; ni < NI; ni++) {
      int n = wn + ni * 16 + c15;
      float bv = bias[n];
#pragma unroll
      for (int rr = 0; rr < 4; rr++) {
        int m = m0 + mi * 16 + quad * 4 + rr;
        if (m < Nn) {
          float v = acc[mi][ni][rr] + bv;
          if (RELU) v = v > 0.f ? v : 0.f;
          if (OUTBF16) ((unsigned short*)outp)[(size_t)m * Nld + n] = f2bf(v);
          else         ((float*)outp)[(size_t)m * Nld + n] = v;
        }
      }
    }
  }
}

extern "C" void kernel_launch(void* const* d_in, const int* in_sizes, int n_in,
                              void* d_out, int out_size, void* d_ws, size_t ws_size,
                              hipStream_t stream) {
  const float* x     = (const float*)d_in[0];
  const int*   ei    = (const int*)d_in[1];   // [2, E]: src row then dst row
  const int*   et    = (const int*)d_in[2];   // [E]
  const float* W1    = (const float*)d_in[3]; // [2048,256]
  const float* root1 = (const float*)d_in[4]; // [256,256]
  const float* b1    = (const float*)d_in[5];
  const float* W2    = (const float*)d_in[6]; // [2048,128]
  const float* root2 = (const float*)d_in[7]; // [256,128]
  const float* b2    = (const float*)d_in[8];

  const int N = in_sizes[0] / F;              // 50000
  const int E = in_sizes[2];                  // 800000
  const int nbins = N * RELS;                 // 400000
  const int Mpad = ((N + 63) / 64) * 64;      // 50048 (div by 64)
  const int nsb = (nbins + SCAN_CHUNK - 1) / SCAN_CHUNK;

  char* base = (char*)d_ws;
  size_t off = 0;
  auto alloc = [&](size_t bytes) {
    void* r = base + off;
    off = (off + bytes + 511) & ~(size_t)511;
    return r;
  };
  unsigned short* Wt1  = (unsigned short*)alloc((size_t)2 * NKT * TSZ * 2);  // 256 cols
  unsigned short* Wt2  = (unsigned short*)alloc((size_t)1 * NKT * TSZ * 2);  // 128 cols
  int*            cnt  = (int*)alloc((size_t)nbins * 4);
  int*            strt = (int*)alloc((size_t)(nbins + 1) * 4);
  int*            bsum = (int*)alloc((size_t)(nsb + 1) * 4);
  unsigned int*   ssr2 = (unsigned int*)alloc((size_t)E * 4);
  unsigned short* xb   = (unsigned short*)alloc((size_t)Mpad * F * 2);  // bf16 x
  unsigned short* h    = (unsigned short*)alloc((size_t)Mpad * F * 2);  // bf16 h
  (void)ws_size; (void)n_in; (void)out_size;

  hipMemsetAsync(cnt, 0, (size_t)nbins * 4, stream);
  k_xb<<<(N * 64 + 255) / 256, 256, 0, stream>>>(x, xb, N);
  k_wt<<<(256 * KDIM + 255) / 256, 256, 0, stream>>>(W1, root1, Wt1, 256);
  k_wt<<<(128 * KDIM + 255) / 256, 256, 0, stream>>>(W2, root2, Wt2, 128);
  k_count<<<(E + 255) / 256, 256, 0, stream>>>(ei, et, cnt, E, N);
  k_scan1<<<nsb, 256, 0, stream>>>(cnt, strt, bsum, nbins);
  k_scan2<<<1, 1024, 0, stream>>>(bsum, nsb);
  k_scan3<<<(nbins + 255) / 256, 256, 0, stream>>>(strt, bsum, nbins, nsb);
  hipMemsetAsync(cnt, 0, (size_t)nbins * 4, stream);  // reuse as cursor
  k_scatter<<<(E + 255) / 256, 256, 0, stream>>>(ei, et, strt, cnt, ssr2, E, N);

  // Layer 1: stream-gather x (bf16, L3-resident) -> h. No A materialization.
  k_fused<4, true, true><<<Mpad / 64, 256, 0, stream>>>(xb, Wt1, strt, ssr2, b1, h, N);
  // Layer 2: stream-gather h -> output (fp32).
  k_fused<2, false, false><<<Mpad / 64, 256, 0, stream>>>(h, Wt2, strt, ssr2, b2, d_out, N);
}